// Round 10
// baseline (218.787 us; speedup 1.0000x reference)
//
#include <hip/hip_runtime.h>
#include <hip/hip_bf16.h>
#include <math.h>

typedef __bf16 bf16x8 __attribute__((ext_vector_type(8)));
typedef float floatx4 __attribute__((ext_vector_type(4)));

#define BM 128
#define BN 128

__device__ __forceinline__ void load_lds16(const void* g, void* l) {
    __builtin_amdgcn_global_load_lds(
        (const __attribute__((address_space(1))) void*)g,
        (__attribute__((address_space(3))) void*)l, 16, 0, 0);
}

// ---------- prep kernels ----------
__global__ __launch_bounds__(256)
void cvt_bf16_kernel(const float* __restrict__ in, __hip_bfloat16* __restrict__ out, int n8)
{
    int i = (blockIdx.x * 256 + threadIdx.x);
    if (i >= n8) return;
    const float4 a = *reinterpret_cast<const float4*>(in + (size_t)i * 8);
    const float4 b = *reinterpret_cast<const float4*>(in + (size_t)i * 8 + 4);
    union { __hip_bfloat162 h[4]; uint4 u; } pk;
    pk.h[0] = __float22bfloat162_rn(make_float2(a.x, a.y));
    pk.h[1] = __float22bfloat162_rn(make_float2(a.z, a.w));
    pk.h[2] = __float22bfloat162_rn(make_float2(b.x, b.y));
    pk.h[3] = __float22bfloat162_rn(make_float2(b.z, b.w));
    *reinterpret_cast<uint4*>(out + (size_t)i * 8) = pk.u;
}

// in [R][C] f32 -> out [C][R] bf16 (64x64 tiles)
__global__ __launch_bounds__(256)
void transpose_cvt_kernel(const float* __restrict__ in, __hip_bfloat16* __restrict__ out,
                          int R, int C)
{
    __shared__ float Ts[64][68];
    const int c0 = blockIdx.x * 64;
    const int r0 = blockIdx.y * 64;
    const int t  = threadIdx.x;
    const int lr = t >> 2;
    const int lc = (t & 3) * 16;
    #pragma unroll
    for (int j = 0; j < 16; j += 4) {
        float4 v = *reinterpret_cast<const float4*>(in + (size_t)(r0 + lr) * C + c0 + lc + j);
        Ts[lr][lc + j + 0] = v.x;
        Ts[lr][lc + j + 1] = v.y;
        Ts[lr][lc + j + 2] = v.z;
        Ts[lr][lc + j + 3] = v.w;
    }
    __syncthreads();
    const int oc = t >> 2;
    const int rs = (t & 3) * 16;
    __hip_bfloat16 tmp[16];
    #pragma unroll
    for (int j = 0; j < 16; ++j)
        tmp[j] = __float2bfloat16(Ts[rs + j][oc]);
    __hip_bfloat16* op = out + (size_t)(c0 + oc) * R + r0 + rs;
    *reinterpret_cast<uint4*>(op)     = *reinterpret_cast<uint4*>(tmp);
    *reinterpret_cast<uint4*>(op + 8) = *reinterpret_cast<uint4*>(tmp + 8);
}

// ---------- GEMM ----------
// EPI 0: QKV + RoPE -> Q/K [BH][T][64] (Q pre-scaled by 0.125*log2e), V^T [BH][64][T]
// EPI 1: proj + bias -> Out f32 [M][N]
// CONV 0: A bf16 [M][K], B bf16 [N][K]; global_load_lds DMA staging, swizzled LDS.
//   BKT=32: measured-best at >=3 blocks/CU (barrier drains hidden by co-resident blocks)
//   BKT=64: measured-best at 1 block/CU (fewer drains, nothing to overlap anyway)
// CONV 1: fallback - A f32 [M][K] (EPI0) / bf16 (EPI1), B f32 [K][N]; BK=32 padded
template<int EPI, int CONV, int BKT, int M, int N, int K>
__global__ __launch_bounds__(256)
void gemm_kernel(const void* __restrict__ Avoid,
                 const void* __restrict__ Bvoid,
                 const float* __restrict__ bias,
                 __hip_bfloat16* __restrict__ Qo,
                 __hip_bfloat16* __restrict__ Ko,
                 __hip_bfloat16* __restrict__ Vt,
                 float* __restrict__ Out)
{
    constexpr int LD = (CONV == 0) ? BKT : 40;
    __shared__ __align__(16) __hip_bfloat16 As[BM][LD];
    __shared__ __align__(16) __hip_bfloat16 Bs[BN][LD];

    const int t    = threadIdx.x;
    const int m0   = blockIdx.y * BM;
    const int n0   = blockIdx.x * BN;
    const int lane = t & 63;
    const int w    = t >> 6;
    const int wm   = (w >> 1) * 64;
    const int wn   = (w & 1) * 64;
    const int quad = lane >> 4;
    const int l16  = lane & 15;

    floatx4 acc[4][4] = {};

    if (CONV == 0 && BKT == 32) {
        // round-7 measured config: chunk = 16 rows x 64 B
        const __hip_bfloat16* A  = (const __hip_bfloat16*)Avoid;
        const __hip_bfloat16* Bt = (const __hip_bfloat16*)Bvoid;
        const int r16 = lane >> 2;
        const int gor = (lane & 3) ^ ((lane >> 3) & 3);
        const int sg  = (quad ^ ((l16 >> 1) & 3)) * 8;

        for (int k0 = 0; k0 < K; k0 += 32) {
            #pragma unroll
            for (int i = 0; i < 2; ++i) {
                int c   = 2 * w + i;              // chunk 0..7
                int row = c * 16 + r16;
                load_lds16(A  + (size_t)(m0 + row) * K + k0 + gor * 8, &As[c * 16][0]);
                load_lds16(Bt + (size_t)(n0 + row) * K + k0 + gor * 8, &Bs[c * 16][0]);
            }
            __syncthreads();
            bf16x8 af[4], bfr[4];
            #pragma unroll
            for (int mf = 0; mf < 4; ++mf)
                af[mf] = *reinterpret_cast<const bf16x8*>(&As[wm + mf * 16 + l16][sg]);
            #pragma unroll
            for (int nf = 0; nf < 4; ++nf)
                bfr[nf] = *reinterpret_cast<const bf16x8*>(&Bs[wn + nf * 16 + l16][sg]);
            #pragma unroll
            for (int mf = 0; mf < 4; ++mf)
                #pragma unroll
                for (int nf = 0; nf < 4; ++nf)
                    acc[mf][nf] = __builtin_amdgcn_mfma_f32_16x16x32_bf16(
                        af[mf], bfr[nf], acc[mf][nf], 0, 0, 0);
            __syncthreads();
        }
    } else if (CONV == 0) {
        // round-9 measured config (BKT=64): chunk = 8 rows x 128 B
        const __hip_bfloat16* A  = (const __hip_bfloat16*)Avoid;
        const __hip_bfloat16* Bt = (const __hip_bfloat16*)Bvoid;
        const int drow = lane >> 3;
        const int gsrc = (lane & 7) ^ drow;
        const int xk   = l16 & 7;

        for (int k0 = 0; k0 < K; k0 += 64) {
            #pragma unroll
            for (int i = 0; i < 4; ++i) {
                int c   = 4 * w + i;            // chunk 0..15
                int row = c * 8 + drow;
                load_lds16(A  + (size_t)(m0 + row) * K + k0 + gsrc * 8, &As[c * 8][0]);
                load_lds16(Bt + (size_t)(n0 + row) * K + k0 + gsrc * 8, &Bs[c * 8][0]);
            }
            __syncthreads();
            #pragma unroll
            for (int kb = 0; kb < 2; ++kb) {
                bf16x8 af[4], bfr[4];
                #pragma unroll
                for (int mf = 0; mf < 4; ++mf)
                    af[mf] = *reinterpret_cast<const bf16x8*>(
                        &As[wm + mf * 16 + l16][((kb * 4 + quad) ^ xk) * 8]);
                #pragma unroll
                for (int nf = 0; nf < 4; ++nf)
                    bfr[nf] = *reinterpret_cast<const bf16x8*>(
                        &Bs[wn + nf * 16 + l16][((kb * 4 + quad) ^ xk) * 8]);
                #pragma unroll
                for (int mf = 0; mf < 4; ++mf)
                    #pragma unroll
                    for (int nf = 0; nf < 4; ++nf)
                        acc[mf][nf] = __builtin_amdgcn_mfma_f32_16x16x32_bf16(
                            af[mf], bfr[nf], acc[mf][nf], 0, 0, 0);
            }
            __syncthreads();
        }
    } else {
        const int sg = quad * 8;
        for (int k0 = 0; k0 < K; k0 += 32) {
            if (EPI == 0) {
                const float* A = (const float*)Avoid;
                #pragma unroll
                for (int i = 0; i < 4; ++i) {
                    int slot = t + i * 256;
                    int row  = slot >> 3;
                    int c4   = (slot & 7) << 2;
                    float4 v = *reinterpret_cast<const float4*>(A + (size_t)(m0 + row) * K + k0 + c4);
                    union { __hip_bfloat162 h2[2]; uint2 u; } pk;
                    pk.h2[0] = __float22bfloat162_rn(make_float2(v.x, v.y));
                    pk.h2[1] = __float22bfloat162_rn(make_float2(v.z, v.w));
                    *reinterpret_cast<uint2*>(&As[row][c4]) = pk.u;
                }
            } else {
                const __hip_bfloat16* A = (const __hip_bfloat16*)Avoid;
                #pragma unroll
                for (int i = 0; i < 2; ++i) {
                    int idx = t + i * 256;
                    int row = idx >> 2;
                    int col = (idx & 3) << 3;
                    *reinterpret_cast<uint4*>(&As[row][col]) =
                        *reinterpret_cast<const uint4*>(A + (size_t)(m0 + row) * K + k0 + col);
                }
            }
            const float* B = (const float*)Bvoid;      // [K][N]
            const int bn  = t & 127;
            const int bkh = (t >> 7) * 16;
            float f[16];
            #pragma unroll
            for (int j = 0; j < 16; ++j)
                f[j] = B[(size_t)(k0 + bkh + j) * N + n0 + bn];
            #pragma unroll
            for (int c = 0; c < 4; ++c) {
                union { __hip_bfloat162 h2[2]; uint2 u; } pk;
                pk.h2[0] = __float22bfloat162_rn(make_float2(f[4*c + 0], f[4*c + 1]));
                pk.h2[1] = __float22bfloat162_rn(make_float2(f[4*c + 2], f[4*c + 3]));
                *reinterpret_cast<uint2*>(&Bs[bn][bkh + 4*c]) = pk.u;
            }
            __syncthreads();

            bf16x8 af[4], bfr[4];
            #pragma unroll
            for (int mf = 0; mf < 4; ++mf)
                af[mf] = *reinterpret_cast<const bf16x8*>(&As[wm + mf * 16 + l16][sg]);
            #pragma unroll
            for (int nf = 0; nf < 4; ++nf)
                bfr[nf] = *reinterpret_cast<const bf16x8*>(&Bs[wn + nf * 16 + l16][sg]);
            #pragma unroll
            for (int mf = 0; mf < 4; ++mf)
                #pragma unroll
                for (int nf = 0; nf < 4; ++nf)
                    acc[mf][nf] = __builtin_amdgcn_mfma_f32_16x16x32_bf16(
                        af[mf], bfr[nf], acc[mf][nf], 0, 0, 0);
            __syncthreads();
        }
    }

    if (EPI == 0) {
        #pragma unroll
        for (int mf = 0; mf < 4; ++mf) {
            #pragma unroll
            for (int nf = 0; nf < 4; ++nf) {
                #pragma unroll
                for (int r = 0; r < 4; ++r) {
                    float v = acc[mf][nf][r];
                    int m  = m0 + wm + mf * 16 + quad * 4 + r;
                    int n  = n0 + wn + nf * 16 + l16;
                    int bb = m >> 11;
                    int tp = m & 2047;
                    int which = n >> 10;         // wave-uniform
                    int dd = n & 63;
                    int h  = (n & 1023) >> 6;
                    float other = __shfl_xor(v, 1);
                    if (which < 2) {
                        int f = dd >> 1;
                        float inv = exp2f((float)f * -0.4152410118609203f); // 10000^(-f/32)
                        float ang = (float)tp * inv;
                        float s, c;
                        __sincosf(ang, &s, &c);
                        v = (dd & 1) ? (other * s + v * c) : (v * c - other * s);
                        if (which == 0) v *= 0.1803368801111137f;   // 0.125 * log2(e)
                    }
                    __hip_bfloat16 bv = __float2bfloat16(v);
                    size_t bh = (size_t)bb * 16 + h;
                    if (which == 0)      Qo[(bh * 2048 + tp) * 64 + dd] = bv;
                    else if (which == 1) Ko[(bh * 2048 + tp) * 64 + dd] = bv;
                    else                 Vt[(bh * 64 + dd) * 2048 + tp] = bv;
                }
            }
        }
    } else {
        #pragma unroll
        for (int mf = 0; mf < 4; ++mf)
            #pragma unroll
            for (int nf = 0; nf < 4; ++nf)
                #pragma unroll
                for (int r = 0; r < 4; ++r) {
                    int m = m0 + wm + mf * 16 + quad * 4 + r;
                    int n = n0 + wn + nf * 16 + l16;
                    Out[(size_t)m * N + n] = acc[mf][nf][r] + bias[n];
                }
    }
}

// ---------- Flash attention ----------
// Pl row stride 76 elems (38 dwords): 16-lane row-strided accesses hit 16
// distinct banks (gcd(38,32)=2) -> conflict-free. Ks/Vs at 72 are 2-way (free).
__global__ __launch_bounds__(256)
void attn_kernel(const __hip_bfloat16* __restrict__ Q,
                 const __hip_bfloat16* __restrict__ Kb,
                 const __hip_bfloat16* __restrict__ Vt,
                 __hip_bfloat16* __restrict__ Y)
{
    const int bh = blockIdx.x;
    const int qt = 31 - (int)blockIdx.y;
    const int bb = bh >> 4;
    const int h  = bh & 15;
    const int t    = threadIdx.x;
    const int w    = t >> 6;
    const int lane = t & 63;
    const int quad = lane >> 4;
    const int l16  = lane & 15;
    const int T = 2048;

    __shared__ __align__(16) __hip_bfloat16 Ks[64][72];
    __shared__ __align__(16) __hip_bfloat16 Vs[64][72];
    __shared__ __align__(16) __hip_bfloat16 Pl[4][16][76];

    const __hip_bfloat16* Qp = Q  + (size_t)bh * T * 64;
    const __hip_bfloat16* Kp = Kb + (size_t)bh * T * 64;
    const __hip_bfloat16* Vp = Vt + (size_t)bh * 64 * T;

    const int qrow0 = qt * 64 + w * 16;

    bf16x8 qa[2];
    #pragma unroll
    for (int kb = 0; kb < 2; ++kb)
        qa[kb] = *reinterpret_cast<const bf16x8*>(
            Qp + (size_t)(qrow0 + l16) * 64 + kb * 32 + quad * 8);

    bf16x8 ones;
    #pragma unroll
    for (int j = 0; j < 8; ++j) ones[j] = (__bf16)1.0f;

    floatx4 o[4] = {};
    floatx4 sums = {};

    const int srow = t >> 2;
    const int sch  = t & 3;
    const int ntiles = qt + 1;

    bf16x8 kreg[2], vreg[2];
    {
        const __hip_bfloat16* kg = Kp + (size_t)srow * 64 + sch * 8;
        kreg[0] = *reinterpret_cast<const bf16x8*>(kg);
        kreg[1] = *reinterpret_cast<const bf16x8*>(kg + 32);
        const __hip_bfloat16* vg = Vp + (size_t)srow * T + sch * 8;
        vreg[0] = *reinterpret_cast<const bf16x8*>(vg);
        vreg[1] = *reinterpret_cast<const bf16x8*>(vg + 32);
    }

    for (int kt = 0; kt < ntiles; ++kt) {
        __syncthreads();
        *reinterpret_cast<bf16x8*>(&Ks[srow][sch * 8])      = kreg[0];
        *reinterpret_cast<bf16x8*>(&Ks[srow][sch * 8 + 32]) = kreg[1];
        *reinterpret_cast<bf16x8*>(&Vs[srow][sch * 8])      = vreg[0];
        *reinterpret_cast<bf16x8*>(&Vs[srow][sch * 8 + 32]) = vreg[1];
        __syncthreads();
        if (kt + 1 < ntiles) {
            const __hip_bfloat16* kg = Kp + (size_t)((kt + 1) * 64 + srow) * 64 + sch * 8;
            kreg[0] = *reinterpret_cast<const bf16x8*>(kg);
            kreg[1] = *reinterpret_cast<const bf16x8*>(kg + 32);
            const __hip_bfloat16* vg = Vp + (size_t)srow * T + (kt + 1) * 64 + sch * 8;
            vreg[0] = *reinterpret_cast<const bf16x8*>(vg);
            vreg[1] = *reinterpret_cast<const bf16x8*>(vg + 32);
        }

        floatx4 sfr[4];
        #pragma unroll
        for (int nf = 0; nf < 4; ++nf) {
            floatx4 s = {};
            #pragma unroll
            for (int kb = 0; kb < 2; ++kb) {
                bf16x8 kf = *reinterpret_cast<const bf16x8*>(&Ks[nf * 16 + l16][kb * 32 + quad * 8]);
                s = __builtin_amdgcn_mfma_f32_16x16x32_bf16(qa[kb], kf, s, 0, 0, 0);
            }
            sfr[nf] = s;
        }
        if (kt == qt) {
            #pragma unroll
            for (int nf = 0; nf < 4; ++nf)
                #pragma unroll
                for (int r = 0; r < 4; ++r) {
                    int qg = w * 16 + quad * 4 + r;
                    int kg = nf * 16 + l16;
                    if (kg > qg) sfr[nf][r] = -INFINITY;
                }
        }
        #pragma unroll
        for (int nf = 0; nf < 4; ++nf)
            #pragma unroll
            for (int r = 0; r < 4; ++r)
                Pl[w][quad * 4 + r][nf * 16 + l16] = __float2bfloat16(exp2f(sfr[nf][r]));
        bf16x8 pa[2];
        #pragma unroll
        for (int kb = 0; kb < 2; ++kb)
            pa[kb] = *reinterpret_cast<const bf16x8*>(&Pl[w][l16][kb * 32 + quad * 8]);

        sums = __builtin_amdgcn_mfma_f32_16x16x32_bf16(pa[0], ones, sums, 0, 0, 0);
        sums = __builtin_amdgcn_mfma_f32_16x16x32_bf16(pa[1], ones, sums, 0, 0, 0);

        #pragma unroll
        for (int nf = 0; nf < 4; ++nf) {
            #pragma unroll
            for (int kb = 0; kb < 2; ++kb) {
                bf16x8 vb = *reinterpret_cast<const bf16x8*>(&Vs[nf * 16 + l16][kb * 32 + quad * 8]);
                o[nf] = __builtin_amdgcn_mfma_f32_16x16x32_bf16(pa[kb], vb, o[nf], 0, 0, 0);
            }
        }
    }

    #pragma unroll
    for (int r = 0; r < 4; ++r) {
        float inv = 1.0f / sums[r];
        #pragma unroll
        for (int nf = 0; nf < 4; ++nf) {
            float v = o[nf][r] * inv;
            int qrow = qrow0 + quad * 4 + r;
            int dd = nf * 16 + l16;
            Y[((size_t)bb * 2048 + qrow) * 1024 + h * 64 + dd] = __float2bfloat16(v);
        }
    }
}

extern "C" void kernel_launch(void* const* d_in, const int* in_sizes, int n_in,
                              void* d_out, int out_size, void* d_ws, size_t ws_size,
                              hipStream_t stream) {
    const float* x      = (const float*)d_in[0];   // [4096][1024] f32
    const float* w_qkv  = (const float*)d_in[1];   // [1024][3072] f32
    const float* w_proj = (const float*)d_in[2];   // [1024][1024] f32
    const float* b_proj = (const float*)d_in[3];   // [1024]       f32
    float* out = (float*)d_out;                    // [4096][1024] f32

    const size_t NELT = (size_t)4096 * 1024;
    const size_t WQKV = (size_t)3072 * 1024;
    const size_t WPRJ = (size_t)1024 * 1024;
    const size_t need_main = (4 * NELT + WQKV + WPRJ) * 2;   // 40 MiB
    const size_t need_fb   = 3 * NELT * 2;                   // 24 MiB

    dim3 blk(256);

    if (ws_size >= need_main) {
        __hip_bfloat16* Q      = (__hip_bfloat16*)d_ws;
        __hip_bfloat16* Kb     = Q   + NELT;
        __hip_bfloat16* Vt     = Kb  + NELT;
        __hip_bfloat16* xb     = Vt  + NELT;     // x bf16; later reused for Y
        __hip_bfloat16* wqkvT  = xb  + NELT;     // [3072][1024]
        __hip_bfloat16* wprjT  = wqkvT + WQKV;   // [1024][1024]

        cvt_bf16_kernel<<<dim3((NELT / 8 + 255) / 256), blk, 0, stream>>>(x, xb, NELT / 8);
        transpose_cvt_kernel<<<dim3(3072 / 64, 1024 / 64), blk, 0, stream>>>(w_qkv, wqkvT, 1024, 3072);
        transpose_cvt_kernel<<<dim3(1024 / 64, 1024 / 64), blk, 0, stream>>>(w_proj, wprjT, 1024, 1024);

        // gemm0: 768 blocks = 3/CU -> BK=32 (barrier drains hidden by co-resident blocks)
        gemm_kernel<0, 0, 32, 4096, 3072, 1024><<<dim3(24, 32), blk, 0, stream>>>(
            xb, wqkvT, nullptr, Q, Kb, Vt, nullptr);
        attn_kernel<<<dim3(32, 32), blk, 0, stream>>>(Q, Kb, Vt, xb);
        // gemm1: 256 blocks = 1/CU -> BK=64 (nothing to overlap; amortize drains)
        gemm_kernel<1, 0, 64, 4096, 1024, 1024><<<dim3(8, 32), blk, 0, stream>>>(
            xb, wprjT, b_proj, nullptr, nullptr, nullptr, out);
    } else if (ws_size >= need_fb) {
        __hip_bfloat16* Q  = (__hip_bfloat16*)d_ws;
        __hip_bfloat16* Kb = Q  + NELT;
        __hip_bfloat16* Vt = Kb + NELT;

        gemm_kernel<0, 1, 32, 4096, 3072, 1024><<<dim3(24, 32), blk, 0, stream>>>(
            x, w_qkv, nullptr, Q, Kb, Vt, nullptr);
        attn_kernel<<<dim3(32, 32), blk, 0, stream>>>(Q, Kb, Vt, (__hip_bfloat16*)d_out);
        hipMemcpyAsync(Q, d_out, NELT * sizeof(__hip_bfloat16), hipMemcpyDeviceToDevice, stream);
        gemm_kernel<1, 1, 32, 4096, 1024, 1024><<<dim3(8, 32), blk, 0, stream>>>(
            Q, w_proj, b_proj, nullptr, nullptr, nullptr, out);
    } else {
        hipMemsetAsync(d_out, 0x44, (size_t)out_size * sizeof(float), stream);
    }
}

// Round 11
// 216.110 us; speedup vs baseline: 1.0124x; 1.0124x over previous
//
#include <hip/hip_runtime.h>
#include <hip/hip_bf16.h>
#include <math.h>

typedef __bf16 bf16x8 __attribute__((ext_vector_type(8)));
typedef float floatx4 __attribute__((ext_vector_type(4)));

#define BM 128
#define BN 128

__device__ __forceinline__ void load_lds16(const void* g, void* l) {
    __builtin_amdgcn_global_load_lds(
        (const __attribute__((address_space(1))) void*)g,
        (__attribute__((address_space(3))) void*)l, 16, 0, 0);
}

// ---------- prep kernels ----------
__global__ __launch_bounds__(256)
void cvt_bf16_kernel(const float* __restrict__ in, __hip_bfloat16* __restrict__ out, int n8)
{
    int i = (blockIdx.x * 256 + threadIdx.x);
    if (i >= n8) return;
    const float4 a = *reinterpret_cast<const float4*>(in + (size_t)i * 8);
    const float4 b = *reinterpret_cast<const float4*>(in + (size_t)i * 8 + 4);
    union { __hip_bfloat162 h[4]; uint4 u; } pk;
    pk.h[0] = __float22bfloat162_rn(make_float2(a.x, a.y));
    pk.h[1] = __float22bfloat162_rn(make_float2(a.z, a.w));
    pk.h[2] = __float22bfloat162_rn(make_float2(b.x, b.y));
    pk.h[3] = __float22bfloat162_rn(make_float2(b.z, b.w));
    *reinterpret_cast<uint4*>(out + (size_t)i * 8) = pk.u;
}

// in [R][C] f32 -> out [C][R] bf16 (64x64 tiles)
__global__ __launch_bounds__(256)
void transpose_cvt_kernel(const float* __restrict__ in, __hip_bfloat16* __restrict__ out,
                          int R, int C)
{
    __shared__ float Ts[64][68];
    const int c0 = blockIdx.x * 64;
    const int r0 = blockIdx.y * 64;
    const int t  = threadIdx.x;
    const int lr = t >> 2;
    const int lc = (t & 3) * 16;
    #pragma unroll
    for (int j = 0; j < 16; j += 4) {
        float4 v = *reinterpret_cast<const float4*>(in + (size_t)(r0 + lr) * C + c0 + lc + j);
        Ts[lr][lc + j + 0] = v.x;
        Ts[lr][lc + j + 1] = v.y;
        Ts[lr][lc + j + 2] = v.z;
        Ts[lr][lc + j + 3] = v.w;
    }
    __syncthreads();
    const int oc = t >> 2;
    const int rs = (t & 3) * 16;
    __hip_bfloat16 tmp[16];
    #pragma unroll
    for (int j = 0; j < 16; ++j)
        tmp[j] = __float2bfloat16(Ts[rs + j][oc]);
    __hip_bfloat16* op = out + (size_t)(c0 + oc) * R + r0 + rs;
    *reinterpret_cast<uint4*>(op)     = *reinterpret_cast<uint4*>(tmp);
    *reinterpret_cast<uint4*>(op + 8) = *reinterpret_cast<uint4*>(tmp + 8);
}

// ---------- GEMM ----------
// EPI 0: QKV + RoPE -> Q/K [BH][T][64] (Q pre-scaled by 0.125*log2e), V^T [BH][64][T]
// EPI 1: proj + bias -> Out f32 [M][N]
// CONV 0: A bf16 [M][K], B bf16 [N][K]; global_load_lds DMA staging, swizzled LDS.
//   BKT=32: measured-best at >=3 blocks/CU (71.2 us, r10)  — barrier drains hidden
//   BKT=64: measured-best at 1 block/CU (r9)               — amortize drains
// CONV 1: fallback - A f32 [M][K] (EPI0) / bf16 (EPI1), B f32 [K][N]; BK=32 padded
template<int EPI, int CONV, int BKT, int M, int N, int K>
__global__ __launch_bounds__(256)
void gemm_kernel(const void* __restrict__ Avoid,
                 const void* __restrict__ Bvoid,
                 const float* __restrict__ bias,
                 __hip_bfloat16* __restrict__ Qo,
                 __hip_bfloat16* __restrict__ Ko,
                 __hip_bfloat16* __restrict__ Vt,
                 float* __restrict__ Out)
{
    constexpr int LD = (CONV == 0) ? BKT : 40;
    __shared__ __align__(16) __hip_bfloat16 As[BM][LD];
    __shared__ __align__(16) __hip_bfloat16 Bs[BN][LD];

    const int t    = threadIdx.x;
    const int m0   = blockIdx.y * BM;
    const int n0   = blockIdx.x * BN;
    const int lane = t & 63;
    const int w    = t >> 6;
    const int wm   = (w >> 1) * 64;
    const int wn   = (w & 1) * 64;
    const int quad = lane >> 4;
    const int l16  = lane & 15;

    floatx4 acc[4][4] = {};

    if (CONV == 0 && BKT == 32) {
        // round-7/10 measured config: chunk = 16 rows x 64 B
        const __hip_bfloat16* A  = (const __hip_bfloat16*)Avoid;
        const __hip_bfloat16* Bt = (const __hip_bfloat16*)Bvoid;
        const int r16 = lane >> 2;
        const int gor = (lane & 3) ^ ((lane >> 3) & 3);
        const int sg  = (quad ^ ((l16 >> 1) & 3)) * 8;

        for (int k0 = 0; k0 < K; k0 += 32) {
            #pragma unroll
            for (int i = 0; i < 2; ++i) {
                int c   = 2 * w + i;              // chunk 0..7
                int row = c * 16 + r16;
                load_lds16(A  + (size_t)(m0 + row) * K + k0 + gor * 8, &As[c * 16][0]);
                load_lds16(Bt + (size_t)(n0 + row) * K + k0 + gor * 8, &Bs[c * 16][0]);
            }
            __syncthreads();
            bf16x8 af[4], bfr[4];
            #pragma unroll
            for (int mf = 0; mf < 4; ++mf)
                af[mf] = *reinterpret_cast<const bf16x8*>(&As[wm + mf * 16 + l16][sg]);
            #pragma unroll
            for (int nf = 0; nf < 4; ++nf)
                bfr[nf] = *reinterpret_cast<const bf16x8*>(&Bs[wn + nf * 16 + l16][sg]);
            #pragma unroll
            for (int mf = 0; mf < 4; ++mf)
                #pragma unroll
                for (int nf = 0; nf < 4; ++nf)
                    acc[mf][nf] = __builtin_amdgcn_mfma_f32_16x16x32_bf16(
                        af[mf], bfr[nf], acc[mf][nf], 0, 0, 0);
            __syncthreads();
        }
    } else if (CONV == 0) {
        // round-9 measured config (BKT=64): chunk = 8 rows x 128 B
        const __hip_bfloat16* A  = (const __hip_bfloat16*)Avoid;
        const __hip_bfloat16* Bt = (const __hip_bfloat16*)Bvoid;
        const int drow = lane >> 3;
        const int gsrc = (lane & 7) ^ drow;
        const int xk   = l16 & 7;

        for (int k0 = 0; k0 < K; k0 += 64) {
            #pragma unroll
            for (int i = 0; i < 4; ++i) {
                int c   = 4 * w + i;            // chunk 0..15
                int row = c * 8 + drow;
                load_lds16(A  + (size_t)(m0 + row) * K + k0 + gsrc * 8, &As[c * 8][0]);
                load_lds16(Bt + (size_t)(n0 + row) * K + k0 + gsrc * 8, &Bs[c * 8][0]);
            }
            __syncthreads();
            #pragma unroll
            for (int kb = 0; kb < 2; ++kb) {
                bf16x8 af[4], bfr[4];
                #pragma unroll
                for (int mf = 0; mf < 4; ++mf)
                    af[mf] = *reinterpret_cast<const bf16x8*>(
                        &As[wm + mf * 16 + l16][((kb * 4 + quad) ^ xk) * 8]);
                #pragma unroll
                for (int nf = 0; nf < 4; ++nf)
                    bfr[nf] = *reinterpret_cast<const bf16x8*>(
                        &Bs[wn + nf * 16 + l16][((kb * 4 + quad) ^ xk) * 8]);
                #pragma unroll
                for (int mf = 0; mf < 4; ++mf)
                    #pragma unroll
                    for (int nf = 0; nf < 4; ++nf)
                        acc[mf][nf] = __builtin_amdgcn_mfma_f32_16x16x32_bf16(
                            af[mf], bfr[nf], acc[mf][nf], 0, 0, 0);
            }
            __syncthreads();
        }
    } else {
        const int sg = quad * 8;
        for (int k0 = 0; k0 < K; k0 += 32) {
            if (EPI == 0) {
                const float* A = (const float*)Avoid;
                #pragma unroll
                for (int i = 0; i < 4; ++i) {
                    int slot = t + i * 256;
                    int row  = slot >> 3;
                    int c4   = (slot & 7) << 2;
                    float4 v = *reinterpret_cast<const float4*>(A + (size_t)(m0 + row) * K + k0 + c4);
                    union { __hip_bfloat162 h2[2]; uint2 u; } pk;
                    pk.h2[0] = __float22bfloat162_rn(make_float2(v.x, v.y));
                    pk.h2[1] = __float22bfloat162_rn(make_float2(v.z, v.w));
                    *reinterpret_cast<uint2*>(&As[row][c4]) = pk.u;
                }
            } else {
                const __hip_bfloat16* A = (const __hip_bfloat16*)Avoid;
                #pragma unroll
                for (int i = 0; i < 2; ++i) {
                    int idx = t + i * 256;
                    int row = idx >> 2;
                    int col = (idx & 3) << 3;
                    *reinterpret_cast<uint4*>(&As[row][col]) =
                        *reinterpret_cast<const uint4*>(A + (size_t)(m0 + row) * K + k0 + col);
                }
            }
            const float* B = (const float*)Bvoid;      // [K][N]
            const int bn  = t & 127;
            const int bkh = (t >> 7) * 16;
            float f[16];
            #pragma unroll
            for (int j = 0; j < 16; ++j)
                f[j] = B[(size_t)(k0 + bkh + j) * N + n0 + bn];
            #pragma unroll
            for (int c = 0; c < 4; ++c) {
                union { __hip_bfloat162 h2[2]; uint2 u; } pk;
                pk.h2[0] = __float22bfloat162_rn(make_float2(f[4*c + 0], f[4*c + 1]));
                pk.h2[1] = __float22bfloat162_rn(make_float2(f[4*c + 2], f[4*c + 3]));
                *reinterpret_cast<uint2*>(&Bs[bn][bkh + 4*c]) = pk.u;
            }
            __syncthreads();

            bf16x8 af[4], bfr[4];
            #pragma unroll
            for (int mf = 0; mf < 4; ++mf)
                af[mf] = *reinterpret_cast<const bf16x8*>(&As[wm + mf * 16 + l16][sg]);
            #pragma unroll
            for (int nf = 0; nf < 4; ++nf)
                bfr[nf] = *reinterpret_cast<const bf16x8*>(&Bs[wn + nf * 16 + l16][sg]);
            #pragma unroll
            for (int mf = 0; mf < 4; ++mf)
                #pragma unroll
                for (int nf = 0; nf < 4; ++nf)
                    acc[mf][nf] = __builtin_amdgcn_mfma_f32_16x16x32_bf16(
                        af[mf], bfr[nf], acc[mf][nf], 0, 0, 0);
            __syncthreads();
        }
    }

    if (EPI == 0) {
        #pragma unroll
        for (int mf = 0; mf < 4; ++mf) {
            #pragma unroll
            for (int nf = 0; nf < 4; ++nf) {
                #pragma unroll
                for (int r = 0; r < 4; ++r) {
                    float v = acc[mf][nf][r];
                    int m  = m0 + wm + mf * 16 + quad * 4 + r;
                    int n  = n0 + wn + nf * 16 + l16;
                    int bb = m >> 11;
                    int tp = m & 2047;
                    int which = n >> 10;         // wave-uniform
                    int dd = n & 63;
                    int h  = (n & 1023) >> 6;
                    float other = __shfl_xor(v, 1);
                    if (which < 2) {
                        int f = dd >> 1;
                        float inv = exp2f((float)f * -0.4152410118609203f); // 10000^(-f/32)
                        float ang = (float)tp * inv;
                        float s, c;
                        __sincosf(ang, &s, &c);
                        v = (dd & 1) ? (other * s + v * c) : (v * c - other * s);
                        if (which == 0) v *= 0.1803368801111137f;   // 0.125 * log2(e)
                    }
                    __hip_bfloat16 bv = __float2bfloat16(v);
                    size_t bh = (size_t)bb * 16 + h;
                    if (which == 0)      Qo[(bh * 2048 + tp) * 64 + dd] = bv;
                    else if (which == 1) Ko[(bh * 2048 + tp) * 64 + dd] = bv;
                    else                 Vt[(bh * 64 + dd) * 2048 + tp] = bv;
                }
            }
        }
    } else {
        #pragma unroll
        for (int mf = 0; mf < 4; ++mf)
            #pragma unroll
            for (int nf = 0; nf < 4; ++nf)
                #pragma unroll
                for (int r = 0; r < 4; ++r) {
                    int m = m0 + wm + mf * 16 + quad * 4 + r;
                    int n = n0 + wn + nf * 16 + l16;
                    Out[(size_t)m * N + n] = acc[mf][nf][r] + bias[n];
                }
    }
}

// ---------- Flash attention (round-9 measured version; Pl stride 72 = 144 B,
// 16-B aligned so pa reads stay ds_read_b128. 76 broke alignment: -21 us, r10) ----------
__global__ __launch_bounds__(256)
void attn_kernel(const __hip_bfloat16* __restrict__ Q,
                 const __hip_bfloat16* __restrict__ Kb,
                 const __hip_bfloat16* __restrict__ Vt,
                 __hip_bfloat16* __restrict__ Y)
{
    const int bh = blockIdx.x;
    const int qt = 31 - (int)blockIdx.y;
    const int bb = bh >> 4;
    const int h  = bh & 15;
    const int t    = threadIdx.x;
    const int w    = t >> 6;
    const int lane = t & 63;
    const int quad = lane >> 4;
    const int l16  = lane & 15;
    const int T = 2048;

    __shared__ __align__(16) __hip_bfloat16 Ks[64][72];
    __shared__ __align__(16) __hip_bfloat16 Vs[64][72];
    __shared__ __align__(16) __hip_bfloat16 Pl[4][16][72];

    const __hip_bfloat16* Qp = Q  + (size_t)bh * T * 64;
    const __hip_bfloat16* Kp = Kb + (size_t)bh * T * 64;
    const __hip_bfloat16* Vp = Vt + (size_t)bh * 64 * T;

    const int qrow0 = qt * 64 + w * 16;

    bf16x8 qa[2];
    #pragma unroll
    for (int kb = 0; kb < 2; ++kb)
        qa[kb] = *reinterpret_cast<const bf16x8*>(
            Qp + (size_t)(qrow0 + l16) * 64 + kb * 32 + quad * 8);

    bf16x8 ones;
    #pragma unroll
    for (int j = 0; j < 8; ++j) ones[j] = (__bf16)1.0f;

    floatx4 o[4] = {};
    floatx4 sums = {};

    const int srow = t >> 2;
    const int sch  = t & 3;
    const int ntiles = qt + 1;

    bf16x8 kreg[2], vreg[2];
    {
        const __hip_bfloat16* kg = Kp + (size_t)srow * 64 + sch * 8;
        kreg[0] = *reinterpret_cast<const bf16x8*>(kg);
        kreg[1] = *reinterpret_cast<const bf16x8*>(kg + 32);
        const __hip_bfloat16* vg = Vp + (size_t)srow * T + sch * 8;
        vreg[0] = *reinterpret_cast<const bf16x8*>(vg);
        vreg[1] = *reinterpret_cast<const bf16x8*>(vg + 32);
    }

    for (int kt = 0; kt < ntiles; ++kt) {
        __syncthreads();
        *reinterpret_cast<bf16x8*>(&Ks[srow][sch * 8])      = kreg[0];
        *reinterpret_cast<bf16x8*>(&Ks[srow][sch * 8 + 32]) = kreg[1];
        *reinterpret_cast<bf16x8*>(&Vs[srow][sch * 8])      = vreg[0];
        *reinterpret_cast<bf16x8*>(&Vs[srow][sch * 8 + 32]) = vreg[1];
        __syncthreads();
        if (kt + 1 < ntiles) {
            const __hip_bfloat16* kg = Kp + (size_t)((kt + 1) * 64 + srow) * 64 + sch * 8;
            kreg[0] = *reinterpret_cast<const bf16x8*>(kg);
            kreg[1] = *reinterpret_cast<const bf16x8*>(kg + 32);
            const __hip_bfloat16* vg = Vp + (size_t)srow * T + (kt + 1) * 64 + sch * 8;
            vreg[0] = *reinterpret_cast<const bf16x8*>(vg);
            vreg[1] = *reinterpret_cast<const bf16x8*>(vg + 32);
        }

        floatx4 sfr[4];
        #pragma unroll
        for (int nf = 0; nf < 4; ++nf) {
            floatx4 s = {};
            #pragma unroll
            for (int kb = 0; kb < 2; ++kb) {
                bf16x8 kf = *reinterpret_cast<const bf16x8*>(&Ks[nf * 16 + l16][kb * 32 + quad * 8]);
                s = __builtin_amdgcn_mfma_f32_16x16x32_bf16(qa[kb], kf, s, 0, 0, 0);
            }
            sfr[nf] = s;
        }
        if (kt == qt) {
            #pragma unroll
            for (int nf = 0; nf < 4; ++nf)
                #pragma unroll
                for (int r = 0; r < 4; ++r) {
                    int qg = w * 16 + quad * 4 + r;
                    int kg = nf * 16 + l16;
                    if (kg > qg) sfr[nf][r] = -INFINITY;
                }
        }
        #pragma unroll
        for (int nf = 0; nf < 4; ++nf)
            #pragma unroll
            for (int r = 0; r < 4; ++r)
                Pl[w][quad * 4 + r][nf * 16 + l16] = __float2bfloat16(exp2f(sfr[nf][r]));
        bf16x8 pa[2];
        #pragma unroll
        for (int kb = 0; kb < 2; ++kb)
            pa[kb] = *reinterpret_cast<const bf16x8*>(&Pl[w][l16][kb * 32 + quad * 8]);

        sums = __builtin_amdgcn_mfma_f32_16x16x32_bf16(pa[0], ones, sums, 0, 0, 0);
        sums = __builtin_amdgcn_mfma_f32_16x16x32_bf16(pa[1], ones, sums, 0, 0, 0);

        #pragma unroll
        for (int nf = 0; nf < 4; ++nf) {
            #pragma unroll
            for (int kb = 0; kb < 2; ++kb) {
                bf16x8 vb = *reinterpret_cast<const bf16x8*>(&Vs[nf * 16 + l16][kb * 32 + quad * 8]);
                o[nf] = __builtin_amdgcn_mfma_f32_16x16x32_bf16(pa[kb], vb, o[nf], 0, 0, 0);
            }
        }
    }

    #pragma unroll
    for (int r = 0; r < 4; ++r) {
        float inv = 1.0f / sums[r];
        #pragma unroll
        for (int nf = 0; nf < 4; ++nf) {
            float v = o[nf][r] * inv;
            int qrow = qrow0 + quad * 4 + r;
            int dd = nf * 16 + l16;
            Y[((size_t)bb * 2048 + qrow) * 1024 + h * 64 + dd] = __float2bfloat16(v);
        }
    }
}

extern "C" void kernel_launch(void* const* d_in, const int* in_sizes, int n_in,
                              void* d_out, int out_size, void* d_ws, size_t ws_size,
                              hipStream_t stream) {
    const float* x      = (const float*)d_in[0];   // [4096][1024] f32
    const float* w_qkv  = (const float*)d_in[1];   // [1024][3072] f32
    const float* w_proj = (const float*)d_in[2];   // [1024][1024] f32
    const float* b_proj = (const float*)d_in[3];   // [1024]       f32
    float* out = (float*)d_out;                    // [4096][1024] f32

    const size_t NELT = (size_t)4096 * 1024;
    const size_t WQKV = (size_t)3072 * 1024;
    const size_t WPRJ = (size_t)1024 * 1024;
    const size_t need_main = (4 * NELT + WQKV + WPRJ) * 2;   // 40 MiB
    const size_t need_fb   = 3 * NELT * 2;                   // 24 MiB

    dim3 blk(256);

    if (ws_size >= need_main) {
        __hip_bfloat16* Q      = (__hip_bfloat16*)d_ws;
        __hip_bfloat16* Kb     = Q   + NELT;
        __hip_bfloat16* Vt     = Kb  + NELT;
        __hip_bfloat16* xb     = Vt  + NELT;     // x bf16; later reused for Y
        __hip_bfloat16* wqkvT  = xb  + NELT;     // [3072][1024]
        __hip_bfloat16* wprjT  = wqkvT + WQKV;   // [1024][1024]

        cvt_bf16_kernel<<<dim3((NELT / 8 + 255) / 256), blk, 0, stream>>>(x, xb, NELT / 8);
        transpose_cvt_kernel<<<dim3(3072 / 64, 1024 / 64), blk, 0, stream>>>(w_qkv, wqkvT, 1024, 3072);
        transpose_cvt_kernel<<<dim3(1024 / 64, 1024 / 64), blk, 0, stream>>>(w_proj, wprjT, 1024, 1024);

        // gemm0: 768 blocks = 3/CU -> BK=32 (measured 71.2 us, r10)
        gemm_kernel<0, 0, 32, 4096, 3072, 1024><<<dim3(24, 32), blk, 0, stream>>>(
            xb, wqkvT, nullptr, Q, Kb, Vt, nullptr);
        attn_kernel<<<dim3(32, 32), blk, 0, stream>>>(Q, Kb, Vt, xb);
        // gemm1: 256 blocks = 1/CU -> BK=64 (measured r9)
        gemm_kernel<1, 0, 64, 4096, 1024, 1024><<<dim3(8, 32), blk, 0, stream>>>(
            xb, wprjT, b_proj, nullptr, nullptr, nullptr, out);
    } else if (ws_size >= need_fb) {
        __hip_bfloat16* Q  = (__hip_bfloat16*)d_ws;
        __hip_bfloat16* Kb = Q  + NELT;
        __hip_bfloat16* Vt = Kb + NELT;

        gemm_kernel<0, 1, 32, 4096, 3072, 1024><<<dim3(24, 32), blk, 0, stream>>>(
            x, w_qkv, nullptr, Q, Kb, Vt, nullptr);
        attn_kernel<<<dim3(32, 32), blk, 0, stream>>>(Q, Kb, Vt, (__hip_bfloat16*)d_out);
        hipMemcpyAsync(Q, d_out, NELT * sizeof(__hip_bfloat16), hipMemcpyDeviceToDevice, stream);
        gemm_kernel<1, 1, 32, 4096, 1024, 1024><<<dim3(8, 32), blk, 0, stream>>>(
            Q, w_proj, b_proj, nullptr, nullptr, nullptr, out);
    } else {
        hipMemsetAsync(d_out, 0x44, (size_t)out_size * sizeof(float), stream);
    }
}

// Round 12
// 208.019 us; speedup vs baseline: 1.0518x; 1.0389x over previous
//
#include <hip/hip_runtime.h>
#include <hip/hip_bf16.h>
#include <math.h>

typedef __bf16 bf16x8 __attribute__((ext_vector_type(8)));
typedef float floatx4 __attribute__((ext_vector_type(4)));

#define BM 128
#define BN 128

__device__ __forceinline__ void load_lds16(const void* g, void* l) {
    __builtin_amdgcn_global_load_lds(
        (const __attribute__((address_space(1))) void*)g,
        (__attribute__((address_space(3))) void*)l, 16, 0, 0);
}

// ---------- fused prep ----------
// blocks [0,2048): cvt x f32->bf16 (4M elems, 8/thread)
// blocks [2048,2816): transpose w_qkv [1024][3072] -> [3072][1024] bf16 (48x16 tiles)
// blocks [2816,3072): transpose w_proj [1024][1024] -> [1024][1024] bf16 (16x16 tiles)
__device__ __forceinline__
void transpose_tile(const float* __restrict__ in, __hip_bfloat16* __restrict__ out,
                    int R, int C, int c0, int r0, int t)
{
    __shared__ float Ts[64][68];
    const int lr = t >> 2;
    const int lc = (t & 3) * 16;
    #pragma unroll
    for (int j = 0; j < 16; j += 4) {
        float4 v = *reinterpret_cast<const float4*>(in + (size_t)(r0 + lr) * C + c0 + lc + j);
        Ts[lr][lc + j + 0] = v.x;
        Ts[lr][lc + j + 1] = v.y;
        Ts[lr][lc + j + 2] = v.z;
        Ts[lr][lc + j + 3] = v.w;
    }
    __syncthreads();
    const int oc = t >> 2;
    const int rs = (t & 3) * 16;
    __hip_bfloat16 tmp[16];
    #pragma unroll
    for (int j = 0; j < 16; ++j)
        tmp[j] = __float2bfloat16(Ts[rs + j][oc]);
    __hip_bfloat16* op = out + (size_t)(c0 + oc) * R + r0 + rs;
    *reinterpret_cast<uint4*>(op)     = *reinterpret_cast<uint4*>(tmp);
    *reinterpret_cast<uint4*>(op + 8) = *reinterpret_cast<uint4*>(tmp + 8);
}

__global__ __launch_bounds__(256)
void prep_kernel(const float* __restrict__ x,      __hip_bfloat16* __restrict__ xb,
                 const float* __restrict__ w_qkv,  __hip_bfloat16* __restrict__ wqkvT,
                 const float* __restrict__ w_proj, __hip_bfloat16* __restrict__ wprjT)
{
    const int bid = blockIdx.x;
    const int t   = threadIdx.x;
    if (bid < 2048) {
        size_t i = (size_t)bid * 256 + t;
        const float4 a = *reinterpret_cast<const float4*>(x + i * 8);
        const float4 b = *reinterpret_cast<const float4*>(x + i * 8 + 4);
        union { __hip_bfloat162 h[4]; uint4 u; } pk;
        pk.h[0] = __float22bfloat162_rn(make_float2(a.x, a.y));
        pk.h[1] = __float22bfloat162_rn(make_float2(a.z, a.w));
        pk.h[2] = __float22bfloat162_rn(make_float2(b.x, b.y));
        pk.h[3] = __float22bfloat162_rn(make_float2(b.z, b.w));
        *reinterpret_cast<uint4*>(xb + i * 8) = pk.u;
    } else if (bid < 2816) {
        int q = bid - 2048;                 // 48 x 16 tiles
        transpose_tile(w_qkv, wqkvT, 1024, 3072, (q % 48) * 64, (q / 48) * 64, t);
    } else {
        int q = bid - 2816;                 // 16 x 16 tiles
        transpose_tile(w_proj, wprjT, 1024, 1024, (q % 16) * 64, (q / 16) * 64, t);
    }
}

// ---------- QKV GEMM (measured-best r10/r11 config: BK=32 DMA, swizzled) ----------
// EPI 0: QKV + RoPE -> Q/K [BH][T][64] (Q pre-scaled by 0.125*log2e), V^T [BH][64][T]
// CONV 0: A bf16 [M][K], B bf16 [N][K].  CONV 1: fallback f32 staging.
template<int EPI, int CONV, int M, int N, int K>
__global__ __launch_bounds__(256)
void gemm_kernel(const void* __restrict__ Avoid,
                 const void* __restrict__ Bvoid,
                 const float* __restrict__ bias,
                 __hip_bfloat16* __restrict__ Qo,
                 __hip_bfloat16* __restrict__ Ko,
                 __hip_bfloat16* __restrict__ Vt,
                 float* __restrict__ Out)
{
    constexpr int LD = (CONV == 0) ? 32 : 40;
    __shared__ __align__(16) __hip_bfloat16 As[BM][LD];
    __shared__ __align__(16) __hip_bfloat16 Bs[BN][LD];

    const int t    = threadIdx.x;
    const int m0   = blockIdx.y * BM;
    const int n0   = blockIdx.x * BN;
    const int lane = t & 63;
    const int w    = t >> 6;
    const int wm   = (w >> 1) * 64;
    const int wn   = (w & 1) * 64;
    const int quad = lane >> 4;
    const int l16  = lane & 15;

    floatx4 acc[4][4] = {};

    if (CONV == 0) {
        const __hip_bfloat16* A  = (const __hip_bfloat16*)Avoid;
        const __hip_bfloat16* Bt = (const __hip_bfloat16*)Bvoid;
        const int r16 = lane >> 2;
        const int gor = (lane & 3) ^ ((lane >> 3) & 3);
        const int sg  = (quad ^ ((l16 >> 1) & 3)) * 8;

        for (int k0 = 0; k0 < K; k0 += 32) {
            #pragma unroll
            for (int i = 0; i < 2; ++i) {
                int c   = 2 * w + i;              // chunk 0..7
                int row = c * 16 + r16;
                load_lds16(A  + (size_t)(m0 + row) * K + k0 + gor * 8, &As[c * 16][0]);
                load_lds16(Bt + (size_t)(n0 + row) * K + k0 + gor * 8, &Bs[c * 16][0]);
            }
            __syncthreads();
            bf16x8 af[4], bfr[4];
            #pragma unroll
            for (int mf = 0; mf < 4; ++mf)
                af[mf] = *reinterpret_cast<const bf16x8*>(&As[wm + mf * 16 + l16][sg]);
            #pragma unroll
            for (int nf = 0; nf < 4; ++nf)
                bfr[nf] = *reinterpret_cast<const bf16x8*>(&Bs[wn + nf * 16 + l16][sg]);
            #pragma unroll
            for (int mf = 0; mf < 4; ++mf)
                #pragma unroll
                for (int nf = 0; nf < 4; ++nf)
                    acc[mf][nf] = __builtin_amdgcn_mfma_f32_16x16x32_bf16(
                        af[mf], bfr[nf], acc[mf][nf], 0, 0, 0);
            __syncthreads();
        }
    } else {
        const int sg = quad * 8;
        for (int k0 = 0; k0 < K; k0 += 32) {
            if (EPI == 0) {
                const float* A = (const float*)Avoid;
                #pragma unroll
                for (int i = 0; i < 4; ++i) {
                    int slot = t + i * 256;
                    int row  = slot >> 3;
                    int c4   = (slot & 7) << 2;
                    float4 v = *reinterpret_cast<const float4*>(A + (size_t)(m0 + row) * K + k0 + c4);
                    union { __hip_bfloat162 h2[2]; uint2 u; } pk;
                    pk.h2[0] = __float22bfloat162_rn(make_float2(v.x, v.y));
                    pk.h2[1] = __float22bfloat162_rn(make_float2(v.z, v.w));
                    *reinterpret_cast<uint2*>(&As[row][c4]) = pk.u;
                }
            } else {
                const __hip_bfloat16* A = (const __hip_bfloat16*)Avoid;
                #pragma unroll
                for (int i = 0; i < 2; ++i) {
                    int idx = t + i * 256;
                    int row = idx >> 2;
                    int col = (idx & 3) << 3;
                    *reinterpret_cast<uint4*>(&As[row][col]) =
                        *reinterpret_cast<const uint4*>(A + (size_t)(m0 + row) * K + k0 + col);
                }
            }
            const float* B = (const float*)Bvoid;      // [K][N]
            const int bn  = t & 127;
            const int bkh = (t >> 7) * 16;
            float f[16];
            #pragma unroll
            for (int j = 0; j < 16; ++j)
                f[j] = B[(size_t)(k0 + bkh + j) * N + n0 + bn];
            #pragma unroll
            for (int c = 0; c < 4; ++c) {
                union { __hip_bfloat162 h2[2]; uint2 u; } pk;
                pk.h2[0] = __float22bfloat162_rn(make_float2(f[4*c + 0], f[4*c + 1]));
                pk.h2[1] = __float22bfloat162_rn(make_float2(f[4*c + 2], f[4*c + 3]));
                *reinterpret_cast<uint2*>(&Bs[bn][bkh + 4*c]) = pk.u;
            }
            __syncthreads();

            bf16x8 af[4], bfr[4];
            #pragma unroll
            for (int mf = 0; mf < 4; ++mf)
                af[mf] = *reinterpret_cast<const bf16x8*>(&As[wm + mf * 16 + l16][sg]);
            #pragma unroll
            for (int nf = 0; nf < 4; ++nf)
                bfr[nf] = *reinterpret_cast<const bf16x8*>(&Bs[wn + nf * 16 + l16][sg]);
            #pragma unroll
            for (int mf = 0; mf < 4; ++mf)
                #pragma unroll
                for (int nf = 0; nf < 4; ++nf)
                    acc[mf][nf] = __builtin_amdgcn_mfma_f32_16x16x32_bf16(
                        af[mf], bfr[nf], acc[mf][nf], 0, 0, 0);
            __syncthreads();
        }
    }

    if (EPI == 0) {
        #pragma unroll
        for (int mf = 0; mf < 4; ++mf) {
            #pragma unroll
            for (int nf = 0; nf < 4; ++nf) {
                #pragma unroll
                for (int r = 0; r < 4; ++r) {
                    float v = acc[mf][nf][r];
                    int m  = m0 + wm + mf * 16 + quad * 4 + r;
                    int n  = n0 + wn + nf * 16 + l16;
                    int bb = m >> 11;
                    int tp = m & 2047;
                    int which = n >> 10;         // wave-uniform
                    int dd = n & 63;
                    int h  = (n & 1023) >> 6;
                    float other = __shfl_xor(v, 1);
                    if (which < 2) {
                        int f = dd >> 1;
                        float inv = exp2f((float)f * -0.4152410118609203f); // 10000^(-f/32)
                        float ang = (float)tp * inv;
                        float s, c;
                        __sincosf(ang, &s, &c);
                        v = (dd & 1) ? (other * s + v * c) : (v * c - other * s);
                        if (which == 0) v *= 0.1803368801111137f;   // 0.125 * log2(e)
                    }
                    __hip_bfloat16 bv = __float2bfloat16(v);
                    size_t bh = (size_t)bb * 16 + h;
                    if (which == 0)      Qo[(bh * 2048 + tp) * 64 + dd] = bv;
                    else if (which == 1) Ko[(bh * 2048 + tp) * 64 + dd] = bv;
                    else                 Vt[(bh * 64 + dd) * 2048 + tp] = bv;
                }
            }
        }
    } else {
        #pragma unroll
        for (int mf = 0; mf < 4; ++mf)
            #pragma unroll
            for (int nf = 0; nf < 4; ++nf)
                #pragma unroll
                for (int r = 0; r < 4; ++r) {
                    int m = m0 + wm + mf * 16 + quad * 4 + r;
                    int n = n0 + wn + nf * 16 + l16;
                    Out[(size_t)m * N + n] = acc[mf][nf][r] + bias[n];
                }
    }
}

// ---------- proj GEMM: BM=128 x BN=64, BK=64, 512 blocks = 2/CU ----------
// A = Y bf16 [4096][1024], B = wprjT bf16 [1024][1024], Out f32 + bias.
// Waves split M 4x32; per wave acc[2][4]; same BK=64 DMA chunk + XOR swizzle as r9.
__global__ __launch_bounds__(256)
void proj_kernel(const __hip_bfloat16* __restrict__ A,
                 const __hip_bfloat16* __restrict__ Bt,
                 const float* __restrict__ bias,
                 float* __restrict__ Out)
{
    constexpr int K = 1024, N = 1024;
    __shared__ __align__(16) __hip_bfloat16 As[128][64];
    __shared__ __align__(16) __hip_bfloat16 Bs[64][64];

    const int t    = threadIdx.x;
    const int m0   = blockIdx.y * 128;
    const int n0   = blockIdx.x * 64;
    const int lane = t & 63;
    const int w    = t >> 6;
    const int wm   = w * 32;
    const int quad = lane >> 4;
    const int l16  = lane & 15;

    const int drow = lane >> 3;                 // 0..7
    const int gsrc = (lane & 7) ^ drow;         // swizzled source group
    const int xk   = l16 & 7;

    floatx4 acc[2][4] = {};

    for (int k0 = 0; k0 < K; k0 += 64) {
        // A: 16 chunks of 8 rows; wave w does chunks [4w,4w+4)
        #pragma unroll
        for (int i = 0; i < 4; ++i) {
            int c   = 4 * w + i;
            int row = c * 8 + drow;
            load_lds16(A + (size_t)(m0 + row) * K + k0 + gsrc * 8, &As[c * 8][0]);
        }
        // B: 8 chunks; wave w does chunks [2w,2w+2)
        #pragma unroll
        for (int i = 0; i < 2; ++i) {
            int c   = 2 * w + i;
            int row = c * 8 + drow;
            load_lds16(Bt + (size_t)(n0 + row) * K + k0 + gsrc * 8, &Bs[c * 8][0]);
        }
        __syncthreads();
        #pragma unroll
        for (int kb = 0; kb < 2; ++kb) {
            const int slot = ((kb * 4 + quad) ^ xk) * 8;
            bf16x8 af[2], bfr[4];
            #pragma unroll
            for (int mf = 0; mf < 2; ++mf)
                af[mf] = *reinterpret_cast<const bf16x8*>(&As[wm + mf * 16 + l16][slot]);
            #pragma unroll
            for (int nf = 0; nf < 4; ++nf)
                bfr[nf] = *reinterpret_cast<const bf16x8*>(&Bs[nf * 16 + l16][slot]);
            #pragma unroll
            for (int mf = 0; mf < 2; ++mf)
                #pragma unroll
                for (int nf = 0; nf < 4; ++nf)
                    acc[mf][nf] = __builtin_amdgcn_mfma_f32_16x16x32_bf16(
                        af[mf], bfr[nf], acc[mf][nf], 0, 0, 0);
        }
        __syncthreads();
    }

    #pragma unroll
    for (int mf = 0; mf < 2; ++mf)
        #pragma unroll
        for (int nf = 0; nf < 4; ++nf)
            #pragma unroll
            for (int r = 0; r < 4; ++r) {
                int m = m0 + wm + mf * 16 + quad * 4 + r;
                int n = n0 + nf * 16 + l16;
                Out[(size_t)m * N + n] = acc[mf][nf][r] + bias[n];
            }
}

// ---------- Flash attention (r11 version, frozen) ----------
__global__ __launch_bounds__(256)
void attn_kernel(const __hip_bfloat16* __restrict__ Q,
                 const __hip_bfloat16* __restrict__ Kb,
                 const __hip_bfloat16* __restrict__ Vt,
                 __hip_bfloat16* __restrict__ Y)
{
    const int bh = blockIdx.x;
    const int qt = 31 - (int)blockIdx.y;
    const int bb = bh >> 4;
    const int h  = bh & 15;
    const int t    = threadIdx.x;
    const int w    = t >> 6;
    const int lane = t & 63;
    const int quad = lane >> 4;
    const int l16  = lane & 15;
    const int T = 2048;

    __shared__ __align__(16) __hip_bfloat16 Ks[64][72];
    __shared__ __align__(16) __hip_bfloat16 Vs[64][72];
    __shared__ __align__(16) __hip_bfloat16 Pl[4][16][72];

    const __hip_bfloat16* Qp = Q  + (size_t)bh * T * 64;
    const __hip_bfloat16* Kp = Kb + (size_t)bh * T * 64;
    const __hip_bfloat16* Vp = Vt + (size_t)bh * 64 * T;

    const int qrow0 = qt * 64 + w * 16;

    bf16x8 qa[2];
    #pragma unroll
    for (int kb = 0; kb < 2; ++kb)
        qa[kb] = *reinterpret_cast<const bf16x8*>(
            Qp + (size_t)(qrow0 + l16) * 64 + kb * 32 + quad * 8);

    bf16x8 ones;
    #pragma unroll
    for (int j = 0; j < 8; ++j) ones[j] = (__bf16)1.0f;

    floatx4 o[4] = {};
    floatx4 sums = {};

    const int srow = t >> 2;
    const int sch  = t & 3;
    const int ntiles = qt + 1;

    bf16x8 kreg[2], vreg[2];
    {
        const __hip_bfloat16* kg = Kp + (size_t)srow * 64 + sch * 8;
        kreg[0] = *reinterpret_cast<const bf16x8*>(kg);
        kreg[1] = *reinterpret_cast<const bf16x8*>(kg + 32);
        const __hip_bfloat16* vg = Vp + (size_t)srow * T + sch * 8;
        vreg[0] = *reinterpret_cast<const bf16x8*>(vg);
        vreg[1] = *reinterpret_cast<const bf16x8*>(vg + 32);
    }

    for (int kt = 0; kt < ntiles; ++kt) {
        __syncthreads();
        *reinterpret_cast<bf16x8*>(&Ks[srow][sch * 8])      = kreg[0];
        *reinterpret_cast<bf16x8*>(&Ks[srow][sch * 8 + 32]) = kreg[1];
        *reinterpret_cast<bf16x8*>(&Vs[srow][sch * 8])      = vreg[0];
        *reinterpret_cast<bf16x8*>(&Vs[srow][sch * 8 + 32]) = vreg[1];
        __syncthreads();
        if (kt + 1 < ntiles) {
            const __hip_bfloat16* kg = Kp + (size_t)((kt + 1) * 64 + srow) * 64 + sch * 8;
            kreg[0] = *reinterpret_cast<const bf16x8*>(kg);
            kreg[1] = *reinterpret_cast<const bf16x8*>(kg + 32);
            const __hip_bfloat16* vg = Vp + (size_t)srow * T + (kt + 1) * 64 + sch * 8;
            vreg[0] = *reinterpret_cast<const bf16x8*>(vg);
            vreg[1] = *reinterpret_cast<const bf16x8*>(vg + 32);
        }

        floatx4 sfr[4];
        #pragma unroll
        for (int nf = 0; nf < 4; ++nf) {
            floatx4 s = {};
            #pragma unroll
            for (int kb = 0; kb < 2; ++kb) {
                bf16x8 kf = *reinterpret_cast<const bf16x8*>(&Ks[nf * 16 + l16][kb * 32 + quad * 8]);
                s = __builtin_amdgcn_mfma_f32_16x16x32_bf16(qa[kb], kf, s, 0, 0, 0);
            }
            sfr[nf] = s;
        }
        if (kt == qt) {
            #pragma unroll
            for (int nf = 0; nf < 4; ++nf)
                #pragma unroll
                for (int r = 0; r < 4; ++r) {
                    int qg = w * 16 + quad * 4 + r;
                    int kg = nf * 16 + l16;
                    if (kg > qg) sfr[nf][r] = -INFINITY;
                }
        }
        #pragma unroll
        for (int nf = 0; nf < 4; ++nf)
            #pragma unroll
            for (int r = 0; r < 4; ++r)
                Pl[w][quad * 4 + r][nf * 16 + l16] = __float2bfloat16(exp2f(sfr[nf][r]));
        bf16x8 pa[2];
        #pragma unroll
        for (int kb = 0; kb < 2; ++kb)
            pa[kb] = *reinterpret_cast<const bf16x8*>(&Pl[w][l16][kb * 32 + quad * 8]);

        sums = __builtin_amdgcn_mfma_f32_16x16x32_bf16(pa[0], ones, sums, 0, 0, 0);
        sums = __builtin_amdgcn_mfma_f32_16x16x32_bf16(pa[1], ones, sums, 0, 0, 0);

        #pragma unroll
        for (int nf = 0; nf < 4; ++nf) {
            #pragma unroll
            for (int kb = 0; kb < 2; ++kb) {
                bf16x8 vb = *reinterpret_cast<const bf16x8*>(&Vs[nf * 16 + l16][kb * 32 + quad * 8]);
                o[nf] = __builtin_amdgcn_mfma_f32_16x16x32_bf16(pa[kb], vb, o[nf], 0, 0, 0);
            }
        }
    }

    #pragma unroll
    for (int r = 0; r < 4; ++r) {
        float inv = 1.0f / sums[r];
        #pragma unroll
        for (int nf = 0; nf < 4; ++nf) {
            float v = o[nf][r] * inv;
            int qrow = qrow0 + quad * 4 + r;
            int dd = nf * 16 + l16;
            Y[((size_t)bb * 2048 + qrow) * 1024 + h * 64 + dd] = __float2bfloat16(v);
        }
    }
}

extern "C" void kernel_launch(void* const* d_in, const int* in_sizes, int n_in,
                              void* d_out, int out_size, void* d_ws, size_t ws_size,
                              hipStream_t stream) {
    const float* x      = (const float*)d_in[0];   // [4096][1024] f32
    const float* w_qkv  = (const float*)d_in[1];   // [1024][3072] f32
    const float* w_proj = (const float*)d_in[2];   // [1024][1024] f32
    const float* b_proj = (const float*)d_in[3];   // [1024]       f32
    float* out = (float*)d_out;                    // [4096][1024] f32

    const size_t NELT = (size_t)4096 * 1024;
    const size_t WQKV = (size_t)3072 * 1024;
    const size_t WPRJ = (size_t)1024 * 1024;
    const size_t need_main = (4 * NELT + WQKV + WPRJ) * 2;   // 40 MiB
    const size_t need_fb   = 3 * NELT * 2;                   // 24 MiB

    dim3 blk(256);

    if (ws_size >= need_main) {
        __hip_bfloat16* Q      = (__hip_bfloat16*)d_ws;
        __hip_bfloat16* Kb     = Q   + NELT;
        __hip_bfloat16* Vt     = Kb  + NELT;
        __hip_bfloat16* xb     = Vt  + NELT;     // x bf16; later reused for Y
        __hip_bfloat16* wqkvT  = xb  + NELT;     // [3072][1024]
        __hip_bfloat16* wprjT  = wqkvT + WQKV;   // [1024][1024]

        prep_kernel<<<dim3(3072), blk, 0, stream>>>(x, xb, w_qkv, wqkvT, w_proj, wprjT);

        // gemm0: 768 blocks = 3/CU, BK=32 (measured 71.2 us)
        gemm_kernel<0, 0, 4096, 3072, 1024><<<dim3(24, 32), blk, 0, stream>>>(
            xb, wqkvT, nullptr, Q, Kb, Vt, nullptr);
        attn_kernel<<<dim3(32, 32), blk, 0, stream>>>(Q, Kb, Vt, xb);
        // proj: 512 blocks = 2/CU, BM=128 x BN=64, BK=64
        proj_kernel<<<dim3(16, 32), blk, 0, stream>>>(xb, wprjT, b_proj, out);
    } else if (ws_size >= need_fb) {
        __hip_bfloat16* Q  = (__hip_bfloat16*)d_ws;
        __hip_bfloat16* Kb = Q  + NELT;
        __hip_bfloat16* Vt = Kb + NELT;

        gemm_kernel<0, 1, 4096, 3072, 1024><<<dim3(24, 32), blk, 0, stream>>>(
            x, w_qkv, nullptr, Q, Kb, Vt, nullptr);
        attn_kernel<<<dim3(32, 32), blk, 0, stream>>>(Q, Kb, Vt, (__hip_bfloat16*)d_out);
        hipMemcpyAsync(Q, d_out, NELT * sizeof(__hip_bfloat16), hipMemcpyDeviceToDevice, stream);
        gemm_kernel<1, 1, 4096, 1024, 1024><<<dim3(8, 32), blk, 0, stream>>>(
            Q, w_proj, b_proj, nullptr, nullptr, nullptr, out);
    } else {
        hipMemsetAsync(d_out, 0x44, (size_t)out_size * sizeof(float), stream);
    }
}